// Round 4
// baseline (545.500 us; speedup 1.0000x reference)
//
#include <hip/hip_runtime.h>
#include <hip/hip_fp16.h>

typedef _Float16 h4_t __attribute__((ext_vector_type(4)));
typedef _Float16 h8_t __attribute__((ext_vector_type(8)));
typedef float f4_t __attribute__((ext_vector_type(4)));

#define B_SZ 1024
#define N_IN 512
#define HID 64
#define N_OUT 256
#define QKN (N_OUT * HID) /* 16384 */

// ---------------------------------------------------------------------------
// Kernel 1: LayerNorm(x) -> h (fp16).  One wave per row of 512.
// ---------------------------------------------------------------------------
__global__ __launch_bounds__(256) void k_ln(const float* __restrict__ x,
                                            const float* __restrict__ gamma,
                                            const float* __restrict__ beta,
                                            _Float16* __restrict__ h16) {
    int tid = threadIdx.x;
    int wave = tid >> 6, lane = tid & 63;
    int row = blockIdx.x * 4 + wave;
    const float4* xr = (const float4*)(x + (size_t)row * N_IN);
    float4 a = xr[lane];
    float4 b = xr[lane + 64];
    float s = a.x + a.y + a.z + a.w + b.x + b.y + b.z + b.w;
    float sq = a.x * a.x + a.y * a.y + a.z * a.z + a.w * a.w +
               b.x * b.x + b.y * b.y + b.z * b.z + b.w * b.w;
    for (int off = 1; off < 64; off <<= 1) {
        s += __shfl_xor(s, off);
        sq += __shfl_xor(sq, off);
    }
    float mean = s * (1.0f / N_IN);
    float var = sq * (1.0f / N_IN) - mean * mean;
    float rstd = rsqrtf(var + 1e-5f);
    float4 g0 = ((const float4*)gamma)[lane];
    float4 g1 = ((const float4*)gamma)[lane + 64];
    float4 e0 = ((const float4*)beta)[lane];
    float4 e1 = ((const float4*)beta)[lane + 64];
    h4_t o0 = {(_Float16)((a.x - mean) * rstd * g0.x + e0.x),
               (_Float16)((a.y - mean) * rstd * g0.y + e0.y),
               (_Float16)((a.z - mean) * rstd * g0.z + e0.z),
               (_Float16)((a.w - mean) * rstd * g0.w + e0.w)};
    h4_t o1 = {(_Float16)((b.x - mean) * rstd * g1.x + e1.x),
               (_Float16)((b.y - mean) * rstd * g1.y + e1.y),
               (_Float16)((b.z - mean) * rstd * g1.z + e1.z),
               (_Float16)((b.w - mean) * rstd * g1.w + e1.w)};
    h4_t* hr = (h4_t*)(h16 + (size_t)row * N_IN);
    hr[lane] = o0;
    hr[lane + 64] = o1;
}

// ---------------------------------------------------------------------------
// Kernel 2: Wq/Wk/Wv (512 x 16384 fp32, K-major) -> W^T (16384 x 512 fp16).
// 64x64 tiles via LDS.
// ---------------------------------------------------------------------------
__global__ __launch_bounds__(256) void k_wt(const float* __restrict__ Wq,
                                            const float* __restrict__ Wk,
                                            const float* __restrict__ Wv,
                                            _Float16* __restrict__ wt) {
    __shared__ _Float16 t[64][65];
    const float* W = blockIdx.z == 0 ? Wq : (blockIdx.z == 1 ? Wk : Wv);
    _Float16* out = wt + (size_t)blockIdx.z * ((size_t)QKN * N_IN);
    int n0 = blockIdx.x * 64, k0 = blockIdx.y * 64;
    int c = threadIdx.x & 63, rq = threadIdx.x >> 6;
    for (int i = 0; i < 16; i++) {
        int r = i * 4 + rq;
        t[r][c] = (_Float16)W[(size_t)(k0 + r) * QKN + n0 + c];
    }
    __syncthreads();
    for (int i = 0; i < 16; i++) {
        int r = i * 4 + rq;
        out[(size_t)(n0 + r) * N_IN + k0 + c] = t[c][r];
    }
}

// ---------------------------------------------------------------------------
// Kernel 3: QKV GEMM, depth-3 counted-vmcnt pipeline.
// 128x128 tile, BK=32, TRIPLE-buffered LDS (48 KB).  Three tiles in flight;
// vmcnt(8) drains the oldest tile only -- tile t's loads get TWO compute
// phases + barriers of latency cover.  Never vmcnt(0) until the tail.
// RAW: own-wave vmcnt -> barrier -> read.  WAR: lgkmcnt(0) -> barrier ->
// stage into the buffer just released.
// C-write: swapped mfma operands -> lane holds 4 consecutive n -> h4 stores.
// ---------------------------------------------------------------------------
__global__ __launch_bounds__(256) void k_qkv(const _Float16* __restrict__ h16,
                                             const _Float16* __restrict__ wt,
                                             const float* __restrict__ bq,
                                             const float* __restrict__ bk,
                                             const float* __restrict__ bv,
                                             _Float16* __restrict__ qkv) {
    __shared__ _Float16 As[3][4096];
    __shared__ _Float16 Bs[3][4096];
    int z = blockIdx.z;
    const _Float16* Wb = wt + (size_t)z * ((size_t)QKN * N_IN);
    const float* bias = z == 0 ? bq : (z == 1 ? bk : bv);
    _Float16* out = qkv + (size_t)z * ((size_t)B_SZ * QKN);
    int m0 = blockIdx.x * 128, n0 = blockIdx.y * 128;
    int tid = threadIdx.x, lane = tid & 63, w = tid >> 6;
    int wm = w & 1, wn = w >> 1;
    int col16 = lane & 15, quad = lane >> 4;

    int idx0 = (w * 2 + 0) * 512 + lane * 8;
    int idx1 = (w * 2 + 1) * 512 + lane * 8;
    int row0 = idx0 >> 5, col0 = idx0 & 31;
    int row1 = idx1 >> 5, col1 = idx1 & 31;
    const _Float16* pa0 = h16 + (size_t)(m0 + row0) * N_IN + col0;
    const _Float16* pa1 = h16 + (size_t)(m0 + row1) * N_IN + col1;
    const _Float16* pb0 = Wb + (size_t)(n0 + row0) * N_IN + col0;
    const _Float16* pb1 = Wb + (size_t)(n0 + row1) * N_IN + col1;

#define STAGE_QKV(buf, kk)                                                          \
    do {                                                                            \
        __builtin_amdgcn_global_load_lds(                                           \
            (const __attribute__((address_space(1))) void*)(pa0 + (kk)),            \
            (__attribute__((address_space(3))) void*)(&As[buf][(w * 2 + 0) * 512]), \
            16, 0, 0);                                                              \
        __builtin_amdgcn_global_load_lds(                                           \
            (const __attribute__((address_space(1))) void*)(pa1 + (kk)),            \
            (__attribute__((address_space(3))) void*)(&As[buf][(w * 2 + 1) * 512]), \
            16, 0, 0);                                                              \
        __builtin_amdgcn_global_load_lds(                                           \
            (const __attribute__((address_space(1))) void*)(pb0 + (kk)),            \
            (__attribute__((address_space(3))) void*)(&Bs[buf][(w * 2 + 0) * 512]), \
            16, 0, 0);                                                              \
        __builtin_amdgcn_global_load_lds(                                           \
            (const __attribute__((address_space(1))) void*)(pb1 + (kk)),            \
            (__attribute__((address_space(3))) void*)(&Bs[buf][(w * 2 + 1) * 512]), \
            16, 0, 0);                                                              \
    } while (0)

#define QKV_COMPUTE(buf)                                                                          \
    do {                                                                                          \
        h8_t af[4], bf[4];                                                                        \
        for (int mt = 0; mt < 4; mt++)                                                            \
            af[mt] = *(const h8_t*)(&As[buf][(wm * 64 + mt * 16 + col16) * 32 + quad * 8]);       \
        for (int nt = 0; nt < 4; nt++)                                                            \
            bf[nt] = *(const h8_t*)(&Bs[buf][(wn * 64 + nt * 16 + col16) * 32 + quad * 8]);       \
        for (int mt = 0; mt < 4; mt++)                                                            \
            for (int nt = 0; nt < 4; nt++)                                                        \
                acc[mt][nt] =                                                                     \
                    __builtin_amdgcn_mfma_f32_16x16x32_f16(bf[nt], af[mt], acc[mt][nt], 0, 0, 0); \
    } while (0)

    f4_t acc[4][4] = {};
    STAGE_QKV(0, 0);
    STAGE_QKV(1, 32);
    STAGE_QKV(2, 64);
#pragma unroll
    for (int t = 0; t < 16; t++) {
        int bi = t % 3;
        if (t <= 13) {
            asm volatile("s_waitcnt vmcnt(8)" ::: "memory");
        } else if (t == 14) {
            asm volatile("s_waitcnt vmcnt(4)" ::: "memory");
        } else {
            asm volatile("s_waitcnt vmcnt(0)" ::: "memory");
        }
        __builtin_amdgcn_s_barrier();
        asm volatile("" ::: "memory");
        QKV_COMPUTE(bi);
        asm volatile("s_waitcnt lgkmcnt(0)" ::: "memory");
        __builtin_amdgcn_s_barrier();
        asm volatile("" ::: "memory");
        if (t + 3 <= 15) STAGE_QKV(bi, (t + 3) * 32);
    }
#undef STAGE_QKV
#undef QKV_COMPUTE

    // C-write: D[row = n (quad*4+r)][col = m (col16)] -> h4 stores
    for (int mt = 0; mt < 4; mt++) {
        int m = m0 + wm * 64 + mt * 16 + col16;
        for (int nt = 0; nt < 4; nt++) {
            int nb = n0 + wn * 64 + nt * 16 + quad * 4;
            f4_t bb = *(const f4_t*)(bias + nb);
            h4_t hv = {(_Float16)(acc[mt][nt][0] + bb[0]),
                       (_Float16)(acc[mt][nt][1] + bb[1]),
                       (_Float16)(acc[mt][nt][2] + bb[2]),
                       (_Float16)(acc[mt][nt][3] + bb[3])};
            *(h4_t*)(out + (size_t)m * QKN + nb) = hv;
        }
    }
}

// ---------------------------------------------------------------------------
// Kernel 4: attention ONLY (no output projection), v5.
// 512 threads (8 waves) per batch; wave w owns 32 query rows.
// K fragments read DIRECT from global (32 KB panel, L1/L2-resident, shared
// by all 8 waves) -- K-LDS eliminated.  LDS = V^T only (32 KB, XOR layout).
// Max-free softmax (logits bounded); denominator reduced once at end.
// Output: A[b][q][h] fp16 (32 MB) for the separate projection GEMM.
// ---------------------------------------------------------------------------
__global__ __launch_bounds__(512) void k_attn(const _Float16* __restrict__ qkv,
                                              _Float16* __restrict__ a16) {
    __shared__ _Float16 lds[16384];  // 32 KB: V^T XOR layout
    int b = blockIdx.x;
    int tid = threadIdx.x, lane = tid & 63, w = tid >> 6;
    int col16 = lane & 15, quad = lane >> 4;
    const _Float16* qb = qkv + (size_t)b * QKN;
    const _Float16* kb = qkv + (size_t)(B_SZ + b) * QKN;
    const _Float16* vb = qkv + (size_t)(2 * B_SZ + b) * QKN;

    // --- stage V^T: Vt[kq][hid^(kq&7)][k3]; (hid16 = w&3, key-half = w>>2) ---
    int k3 = lane & 3;
    int hb = w & 3, kbase2 = (w >> 2) * 128;
    for (int kc2 = 0; kc2 < 2; kc2++) {
        int key = kbase2 + kc2 * 64 + lane;
        h8_t va = *(const h8_t*)(vb + (size_t)key * 64 + hb * 16);
        h8_t vc = *(const h8_t*)(vb + (size_t)key * 64 + hb * 16 + 8);
        int kq = key >> 2;
        int kx = kq & 7;
        _Float16* vp = lds + kq * 256 + k3;
        for (int j = 0; j < 8; j++) vp[(size_t)((hb * 16 + j) ^ kx) * 4] = va[j];
        for (int j = 0; j < 8; j++) vp[(size_t)((hb * 16 + 8 + j) ^ kx) * 4] = vc[j];
    }

    // --- Q fragments for 16x16x32: hid = ki*32 + quad*8 + j ---
    h8_t qf[2][2];
    int qbase = w * 32;
    for (int qt = 0; qt < 2; qt++)
        for (int ki = 0; ki < 2; ki++)
            qf[qt][ki] = *(const h8_t*)(qb + (size_t)(qbase + qt * 16 + col16) * 64 + ki * 32 + quad * 8);

    __syncthreads();  // V ds_writes visible

    f4_t o[4][2] = {};  // [h-tile][q-tile]
    float lrun[2] = {0.f, 0.f};
    const float sc = 0.125f * 1.44269504f;  // scale * log2(e)

    for (int kc = 0; kc < 16; kc++) {
        // K fragments direct from global (L1-resident after first wave)
        h8_t kf0 = *(const h8_t*)(kb + (size_t)(kc * 16 + col16) * 64 + quad * 8);
        h8_t kf1 = *(const h8_t*)(kb + (size_t)(kc * 16 + col16) * 64 + 32 + quad * 8);
        int kqr = kc * 4 + quad, kxr = kqr & 7;
        h4_t vf[4];
        for (int mt = 0; mt < 4; mt++)
            vf[mt] = *(const h4_t*)(lds + kqr * 256 + (size_t)((mt * 16 + col16) ^ kxr) * 4);
        for (int qt = 0; qt < 2; qt++) {
            f4_t s = {};
            s = __builtin_amdgcn_mfma_f32_16x16x32_f16(kf0, qf[qt][0], s, 0, 0, 0);
            s = __builtin_amdgcn_mfma_f32_16x16x32_f16(kf1, qf[qt][1], s, 0, 0, 0);
            // S^T tile: key = quad*4+reg, query = col16; bounded logits -> no max
            float p0 = exp2f(s[0] * sc);
            float p1 = exp2f(s[1] * sc);
            float p2 = exp2f(s[2] * sc);
            float p3 = exp2f(s[3] * sc);
            lrun[qt] += (p0 + p1) + (p2 + p3);
            h4_t pf = {(_Float16)p0, (_Float16)p1, (_Float16)p2, (_Float16)p3};
            for (int mt = 0; mt < 4; mt++)
                o[mt][qt] = __builtin_amdgcn_mfma_f32_16x16x16f16(vf[mt], pf, o[mt][qt], 0, 0, 0);
        }
    }

    // denominator: one reduction over quad groups; normalize; store A fp16
    for (int qt = 0; qt < 2; qt++) {
        float l = lrun[qt];
        l += __shfl_xor(l, 16);
        l += __shfl_xor(l, 32);
        float rl = 1.0f / l;
        int q = qbase + qt * 16 + col16;
        _Float16* ap = a16 + ((size_t)b * N_OUT + q) * HID + quad * 4;
        for (int mt = 0; mt < 4; mt++) {
            f4_t t = o[mt][qt];
            h4_t hv = {(_Float16)(t[0] * rl), (_Float16)(t[1] * rl),
                       (_Float16)(t[2] * rl), (_Float16)(t[3] * rl)};
            *(h4_t*)(ap + mt * 16) = hv;
        }
    }
}

// ---------------------------------------------------------------------------
// Kernel 5: output projection.  out = -relu(A @ Wo + bo), A:(262144 x 64),
// Wo:(64 x 256).  Flat GEMM, K=64 in one shot (no K loop, no main-loop
// barriers).  Wo^T fp16 staged once in LDS with XOR swizzle.  8 waves:
// block tile 128m x 256n, per-wave 64m x 64n.  f4 stores (write-BW bound).
// ---------------------------------------------------------------------------
__global__ __launch_bounds__(512) void k_proj(const _Float16* __restrict__ a16,
                                              const float* __restrict__ Wo,
                                              const float* __restrict__ bo,
                                              float* __restrict__ out) {
    __shared__ _Float16 wt[16384];  // WoT[n][64], XOR-swizzled, 32 KB
    int tid = threadIdx.x, lane = tid & 63, w = tid >> 6;
    int col16 = lane & 15, quad = lane >> 4;
    int wm = w & 1, wn = w >> 1;
    int m0 = blockIdx.x * 128;

    // stage Wo^T: element (n, h) at wt[n*64 + (h ^ ((n&7)<<3))]
    {
        int n = tid & 255, pr = tid >> 8;
        for (int it = 0; it < 8; it++) {
            int h0 = it * 8 + pr * 4;
            h4_t wv = {(_Float16)Wo[(size_t)(h0 + 0) * 256 + n],
                       (_Float16)Wo[(size_t)(h0 + 1) * 256 + n],
                       (_Float16)Wo[(size_t)(h0 + 2) * 256 + n],
                       (_Float16)Wo[(size_t)(h0 + 3) * 256 + n]};
            *(h4_t*)(wt + n * 64 + (h0 ^ ((n & 7) << 3))) = wv;
        }
    }
    __syncthreads();

    // B fragments (A-operand of swapped mfma): row = n, k = ki*32+quad*8+j
    h8_t bf[4][2];
    for (int nt = 0; nt < 4; nt++) {
        int n = wn * 64 + nt * 16 + col16;
        for (int ki = 0; ki < 2; ki++)
            bf[nt][ki] = *(const h8_t*)(wt + n * 64 + ((ki * 32 + quad * 8) ^ ((n & 7) << 3)));
    }
    // A fragments (B-operand): col = m-row, k = ki*32+quad*8+j
    h8_t af[4][2];
    for (int mt = 0; mt < 4; mt++) {
        int row = m0 + wm * 64 + mt * 16 + col16;
        for (int ki = 0; ki < 2; ki++)
            af[mt][ki] = *(const h8_t*)(a16 + (size_t)row * HID + ki * 32 + quad * 8);
    }
    f4_t acc[4][4] = {};
    for (int mt = 0; mt < 4; mt++)
        for (int nt = 0; nt < 4; nt++)
            for (int ki = 0; ki < 2; ki++)
                acc[mt][nt] = __builtin_amdgcn_mfma_f32_16x16x32_f16(bf[nt][ki], af[mt][ki],
                                                                     acc[mt][nt], 0, 0, 0);
    // D[row = n (quad*4+r)][col = m (col16)]; lane: 4 consecutive n -> f4 store
    for (int mt = 0; mt < 4; mt++) {
        size_t row = (size_t)(m0 + wm * 64 + mt * 16 + col16);
        for (int nt = 0; nt < 4; nt++) {
            int nb = wn * 64 + nt * 16 + quad * 4;
            f4_t bb = *(const f4_t*)(bo + nb);
            f4_t v;
            for (int r = 0; r < 4; r++) {
                float t = acc[mt][nt][r] + bb[r];
                v[r] = (t > 0.f) ? -t : 0.f;
            }
            *(f4_t*)(out + row * N_OUT + nb) = v;
        }
    }
}

// ---------------------------------------------------------------------------
extern "C" void kernel_launch(void* const* d_in, const int* in_sizes, int n_in,
                              void* d_out, int out_size, void* d_ws, size_t ws_size,
                              hipStream_t stream) {
    const float* x = (const float*)d_in[0];
    const float* gamma = (const float*)d_in[1];
    const float* beta = (const float*)d_in[2];
    const float* Wq = (const float*)d_in[3];
    const float* bq = (const float*)d_in[4];
    const float* Wk = (const float*)d_in[5];
    const float* bk = (const float*)d_in[6];
    const float* Wv = (const float*)d_in[7];
    const float* bv = (const float*)d_in[8];
    const float* Wo = (const float*)d_in[9];
    const float* bo = (const float*)d_in[10];
    float* out = (float*)d_out;

    _Float16* h16 = (_Float16*)d_ws;                         // 1 MB
    _Float16* wt16 = h16 + (size_t)B_SZ * N_IN;              // 48 MB
    _Float16* qkv16 = wt16 + (size_t)3 * QKN * N_IN;         // 96 MB
    _Float16* a16 = qkv16 + (size_t)3 * B_SZ * QKN;          // 32 MB

    k_ln<<<dim3(B_SZ / 4), 256, 0, stream>>>(x, gamma, beta, h16);
    k_wt<<<dim3(QKN / 64, N_IN / 64, 3), 256, 0, stream>>>(Wq, Wk, Wv, wt16);
    k_qkv<<<dim3(B_SZ / 128, QKN / 128, 3), 256, 0, stream>>>(h16, wt16, bq, bk, bv, qkv16);
    k_attn<<<dim3(B_SZ), 512, 0, stream>>>(qkv16, a16);
    k_proj<<<dim3((B_SZ * N_OUT) / 128), 512, 0, stream>>>(a16, Wo, bo, out);
}

// Round 5
// 498.773 us; speedup vs baseline: 1.0937x; 1.0937x over previous
//
#include <hip/hip_runtime.h>
#include <hip/hip_fp16.h>

typedef _Float16 h4_t __attribute__((ext_vector_type(4)));
typedef _Float16 h8_t __attribute__((ext_vector_type(8)));
typedef float f4_t __attribute__((ext_vector_type(4)));

#define B_SZ 1024
#define N_IN 512
#define HID 64
#define N_OUT 256
#define QKN (N_OUT * HID) /* 16384 */

// ---------------------------------------------------------------------------
// Kernel 1: LayerNorm(x) -> h (fp16).  One wave per row of 512.
// ---------------------------------------------------------------------------
__global__ __launch_bounds__(256) void k_ln(const float* __restrict__ x,
                                            const float* __restrict__ gamma,
                                            const float* __restrict__ beta,
                                            _Float16* __restrict__ h16) {
    int tid = threadIdx.x;
    int wave = tid >> 6, lane = tid & 63;
    int row = blockIdx.x * 4 + wave;
    const float4* xr = (const float4*)(x + (size_t)row * N_IN);
    float4 a = xr[lane];
    float4 b = xr[lane + 64];
    float s = a.x + a.y + a.z + a.w + b.x + b.y + b.z + b.w;
    float sq = a.x * a.x + a.y * a.y + a.z * a.z + a.w * a.w +
               b.x * b.x + b.y * b.y + b.z * b.z + b.w * b.w;
    for (int off = 1; off < 64; off <<= 1) {
        s += __shfl_xor(s, off);
        sq += __shfl_xor(sq, off);
    }
    float mean = s * (1.0f / N_IN);
    float var = sq * (1.0f / N_IN) - mean * mean;
    float rstd = rsqrtf(var + 1e-5f);
    float4 g0 = ((const float4*)gamma)[lane];
    float4 g1 = ((const float4*)gamma)[lane + 64];
    float4 e0 = ((const float4*)beta)[lane];
    float4 e1 = ((const float4*)beta)[lane + 64];
    h4_t o0 = {(_Float16)((a.x - mean) * rstd * g0.x + e0.x),
               (_Float16)((a.y - mean) * rstd * g0.y + e0.y),
               (_Float16)((a.z - mean) * rstd * g0.z + e0.z),
               (_Float16)((a.w - mean) * rstd * g0.w + e0.w)};
    h4_t o1 = {(_Float16)((b.x - mean) * rstd * g1.x + e1.x),
               (_Float16)((b.y - mean) * rstd * g1.y + e1.y),
               (_Float16)((b.z - mean) * rstd * g1.z + e1.z),
               (_Float16)((b.w - mean) * rstd * g1.w + e1.w)};
    h4_t* hr = (h4_t*)(h16 + (size_t)row * N_IN);
    hr[lane] = o0;
    hr[lane + 64] = o1;
}

// ---------------------------------------------------------------------------
// Kernel 2: Wq/Wk/Wv (512 x 16384 fp32, K-major) -> W^T (16384 x 512 fp16).
// 64x64 tiles via LDS.
// ---------------------------------------------------------------------------
__global__ __launch_bounds__(256) void k_wt(const float* __restrict__ Wq,
                                            const float* __restrict__ Wk,
                                            const float* __restrict__ Wv,
                                            _Float16* __restrict__ wt) {
    __shared__ _Float16 t[64][65];
    const float* W = blockIdx.z == 0 ? Wq : (blockIdx.z == 1 ? Wk : Wv);
    _Float16* out = wt + (size_t)blockIdx.z * ((size_t)QKN * N_IN);
    int n0 = blockIdx.x * 64, k0 = blockIdx.y * 64;
    int c = threadIdx.x & 63, rq = threadIdx.x >> 6;
    for (int i = 0; i < 16; i++) {
        int r = i * 4 + rq;
        t[r][c] = (_Float16)W[(size_t)(k0 + r) * QKN + n0 + c];
    }
    __syncthreads();
    for (int i = 0; i < 16; i++) {
        int r = i * 4 + rq;
        out[(size_t)(n0 + r) * N_IN + k0 + c] = t[c][r];
    }
}

// ---------------------------------------------------------------------------
// Kernel 3: QKV GEMM, v3.  256m x 128n tile, 512 threads (8 waves, 4m x 2n),
// BK=32, depth-2 counted-vmcnt pipeline (r3-verified mechanics; 3 loads per
// stage -> vmcnt(3)).  LDS 48 KB double-buffered.
// GRID TRANSPOSED for XCD L2 reuse: x = n-panel (128), y = m-panel (4).
// linear id = x + 128y (+512z) -> XCD = x % 8, so ALL m-blocks sharing one
// wt n-panel land on the SAME XCD -> panel fetched once into that L2
// (old layout spread them across all 8 XCDs).
// C-write: swapped mfma operands -> lane holds 4 consecutive n -> h4 stores.
// ---------------------------------------------------------------------------
__global__ __launch_bounds__(512, 4) void k_qkv(const _Float16* __restrict__ h16,
                                                const _Float16* __restrict__ wt,
                                                const float* __restrict__ bq,
                                                const float* __restrict__ bk,
                                                const float* __restrict__ bv,
                                                _Float16* __restrict__ qkv) {
    __shared__ _Float16 As[2][8192];  // 256 x 32
    __shared__ _Float16 Bs[2][4096];  // 128 x 32
    int z = blockIdx.z;
    const _Float16* Wb = wt + (size_t)z * ((size_t)QKN * N_IN);
    const float* bias = z == 0 ? bq : (z == 1 ? bk : bv);
    _Float16* out = qkv + (size_t)z * ((size_t)B_SZ * QKN);
    int n0 = blockIdx.x * 128;  // x = n-panel
    int m0 = blockIdx.y * 256;  // y = m-panel
    int tid = threadIdx.x, lane = tid & 63, w = tid >> 6;
    int wm = w & 3, wn = w >> 2;
    int col16 = lane & 15, quad = lane >> 4;

    // staging addresses: thread t covers row t>>2, cols (t&3)*8 .. +8
    int arow = tid >> 2;            // 0..127
    int acol = (tid & 3) * 8;
    const _Float16* pa0 = h16 + (size_t)(m0 + arow) * N_IN + acol;        // rows 0..127
    const _Float16* pa1 = h16 + (size_t)(m0 + 128 + arow) * N_IN + acol;  // rows 128..255
    const _Float16* pb0 = Wb + (size_t)(n0 + arow) * N_IN + acol;         // rows 0..127

#define STAGE_QKV(buf, kk)                                                   \
    do {                                                                     \
        __builtin_amdgcn_global_load_lds(                                    \
            (const __attribute__((address_space(1))) void*)(pa0 + (kk)),     \
            (__attribute__((address_space(3))) void*)(&As[buf][w * 512]),    \
            16, 0, 0);                                                       \
        __builtin_amdgcn_global_load_lds(                                    \
            (const __attribute__((address_space(1))) void*)(pa1 + (kk)),     \
            (__attribute__((address_space(3))) void*)(&As[buf][4096 + w * 512]), \
            16, 0, 0);                                                       \
        __builtin_amdgcn_global_load_lds(                                    \
            (const __attribute__((address_space(1))) void*)(pb0 + (kk)),     \
            (__attribute__((address_space(3))) void*)(&Bs[buf][w * 512]),    \
            16, 0, 0);                                                       \
    } while (0)

#define QKV_COMPUTE(buf)                                                                          \
    do {                                                                                          \
        h8_t af[4], bf[4];                                                                        \
        for (int mt = 0; mt < 4; mt++)                                                            \
            af[mt] = *(const h8_t*)(&As[buf][(wm * 64 + mt * 16 + col16) * 32 + quad * 8]);       \
        for (int nt = 0; nt < 4; nt++)                                                            \
            bf[nt] = *(const h8_t*)(&Bs[buf][(wn * 64 + nt * 16 + col16) * 32 + quad * 8]);       \
        for (int mt = 0; mt < 4; mt++)                                                            \
            for (int nt = 0; nt < 4; nt++)                                                        \
                acc[mt][nt] =                                                                     \
                    __builtin_amdgcn_mfma_f32_16x16x32_f16(bf[nt], af[mt], acc[mt][nt], 0, 0, 0); \
    } while (0)

    f4_t acc[4][4] = {};
    STAGE_QKV(0, 0);
    STAGE_QKV(1, 32);
    for (int t = 0; t < 16; t++) {
        int buf = t & 1;
        if (t < 15) {
            asm volatile("s_waitcnt vmcnt(3)" ::: "memory");  // drain stage t only
        } else {
            asm volatile("s_waitcnt vmcnt(0)" ::: "memory");  // tail
        }
        __builtin_amdgcn_s_barrier();
        asm volatile("" ::: "memory");
        QKV_COMPUTE(buf);
        asm volatile("s_waitcnt lgkmcnt(0)" ::: "memory");
        __builtin_amdgcn_s_barrier();
        asm volatile("" ::: "memory");
        if (t + 2 <= 15) STAGE_QKV(buf, (t + 2) * 32);
    }
#undef STAGE_QKV
#undef QKV_COMPUTE

    // C-write: D[row = n (quad*4+r)][col = m (col16)] -> h4 stores
    for (int mt = 0; mt < 4; mt++) {
        int m = m0 + wm * 64 + mt * 16 + col16;
        for (int nt = 0; nt < 4; nt++) {
            int nb = n0 + wn * 64 + nt * 16 + quad * 4;
            f4_t bb = *(const f4_t*)(bias + nb);
            h4_t hv = {(_Float16)(acc[mt][nt][0] + bb[0]),
                       (_Float16)(acc[mt][nt][1] + bb[1]),
                       (_Float16)(acc[mt][nt][2] + bb[2]),
                       (_Float16)(acc[mt][nt][3] + bb[3])};
            *(h4_t*)(out + (size_t)m * QKN + nb) = hv;
        }
    }
}

// ---------------------------------------------------------------------------
// Kernel 4: fused attention + output projection (r3-verified best).
// 512 threads (8 waves) per batch -> 4 waves/SIMD at 64 KB LDS.
// Wave w owns 32 query rows.  Max-free softmax (logits bounded); denominator
// accumulated per-lane, shfl-reduced ONCE at end.
// LDS 64 KB: [0,16K) halves K8[hid/8][key][8] via global_load_lds
//            (phase2: Wo^T); [16K,32K) halves V^T XOR layout.
// ---------------------------------------------------------------------------
__global__ __launch_bounds__(512) void k_attn(const _Float16* __restrict__ qkv,
                                              const float* __restrict__ Wo,
                                              const float* __restrict__ bo,
                                              float* __restrict__ out) {
    __shared__ _Float16 lds[32768];  // 64 KB
    int b = blockIdx.x;
    int tid = threadIdx.x, lane = tid & 63, w = tid >> 6;
    int col16 = lane & 15, quad = lane >> 4;
    const _Float16* qb = qkv + (size_t)b * QKN;
    const _Float16* kb = qkv + (size_t)(B_SZ + b) * QKN;
    const _Float16* vb = qkv + (size_t)(2 * B_SZ + b) * QKN;

    // --- stage K: K8[c8 = hid>>3][key][8], via global_load_lds (16 B) ---
    for (int r = 0; r < 4; r++) {
        int slab = r * 8 + w;  // 0..31, wave-uniform
        int c8 = slab >> 2, kblk = slab & 3;
        __builtin_amdgcn_global_load_lds(
            (const __attribute__((address_space(1))) void*)(kb + (size_t)(kblk * 64 + lane) * 64 + c8 * 8),
            (__attribute__((address_space(3))) void*)(lds + slab * 512),
            16, 0, 0);
    }

    // --- stage V^T: Vt[kq][hid^(kq&7)][k3]; 8 waves: (hid16 = w&3, half = w>>2)
    int k3 = lane & 3;
    int hb = w & 3, kbase2 = (w >> 2) * 128;
    for (int kc2 = 0; kc2 < 2; kc2++) {
        int key = kbase2 + kc2 * 64 + lane;
        h8_t va = *(const h8_t*)(vb + (size_t)key * 64 + hb * 16);
        h8_t vc = *(const h8_t*)(vb + (size_t)key * 64 + hb * 16 + 8);
        int kq = key >> 2;
        int kx = kq & 7;
        _Float16* vp = lds + 16384 + kq * 256 + k3;
        for (int j = 0; j < 8; j++) vp[(size_t)((hb * 16 + j) ^ kx) * 4] = va[j];
        for (int j = 0; j < 8; j++) vp[(size_t)((hb * 16 + 8 + j) ^ kx) * 4] = vc[j];
    }

    // --- Q fragments for 16x16x32: hid = ki*32 + quad*8 + j ---
    h8_t qf[2][2];
    int qbase = w * 32;
    for (int qt = 0; qt < 2; qt++)
        for (int ki = 0; ki < 2; ki++)
            qf[qt][ki] = *(const h8_t*)(qb + (size_t)(qbase + qt * 16 + col16) * 64 + ki * 32 + quad * 8);

    __syncthreads();  // drains global_load_lds + V ds_writes

    f4_t o[4][2] = {};  // [h-tile][q-tile]
    float lrun[2] = {0.f, 0.f};
    const float sc = 0.125f * 1.44269504f;  // scale * log2(e)

    for (int kc = 0; kc < 16; kc++) {
        h8_t kf0 = *(const h8_t*)(lds + (size_t)quad * 2048 + (size_t)(kc * 16 + col16) * 8);
        h8_t kf1 = *(const h8_t*)(lds + (size_t)(4 + quad) * 2048 + (size_t)(kc * 16 + col16) * 8);
        int kqr = kc * 4 + quad, kxr = kqr & 7;
        h4_t vf[4];
        for (int mt = 0; mt < 4; mt++)
            vf[mt] = *(const h4_t*)(lds + 16384 + kqr * 256 +
                                    (size_t)((mt * 16 + col16) ^ kxr) * 4);
        for (int qt = 0; qt < 2; qt++) {
            f4_t s = {};
            s = __builtin_amdgcn_mfma_f32_16x16x32_f16(kf0, qf[qt][0], s, 0, 0, 0);
            s = __builtin_amdgcn_mfma_f32_16x16x32_f16(kf1, qf[qt][1], s, 0, 0, 0);
            // S^T tile: key = quad*4+reg, query = col16; logits bounded -> no max
            float p0 = exp2f(s[0] * sc);
            float p1 = exp2f(s[1] * sc);
            float p2 = exp2f(s[2] * sc);
            float p3 = exp2f(s[3] * sc);
            lrun[qt] += (p0 + p1) + (p2 + p3);
            h4_t pf = {(_Float16)p0, (_Float16)p1, (_Float16)p2, (_Float16)p3};
            for (int mt = 0; mt < 4; mt++)
                o[mt][qt] = __builtin_amdgcn_mfma_f32_16x16x16f16(vf[mt], pf, o[mt][qt], 0, 0, 0);
        }
    }

    // denominator: one reduction over quad groups at the end
    for (int qt = 0; qt < 2; qt++) {
        float l = lrun[qt];
        l += __shfl_xor(l, 16);
        l += __shfl_xor(l, 32);
        lrun[qt] = l;
    }

    // normalize; O's C-layout (q=col16, h=quad*4+reg) == B-operand layout
    h4_t af[2][4];  // [qt][hk]
    for (int qt = 0; qt < 2; qt++) {
        float rl = 1.0f / lrun[qt];
        for (int hk = 0; hk < 4; hk++) {
            f4_t t = o[hk][qt];
            af[qt][hk] = (h4_t){(_Float16)(t[0] * rl), (_Float16)(t[1] * rl),
                                (_Float16)(t[2] * rl), (_Float16)(t[3] * rl)};
        }
    }
    __syncthreads();
    // stage Wo^T -> Wt4[h/4][no][4] over K8's LDS region, b64 writes
    {
        int no = tid & 255, pr = tid >> 8;
        for (int it2 = 0; it2 < 8; it2++) {
            int hh0 = it2 * 8 + pr * 4;
            h4_t wv = {(_Float16)Wo[(size_t)(hh0 + 0) * 256 + no],
                       (_Float16)Wo[(size_t)(hh0 + 1) * 256 + no],
                       (_Float16)Wo[(size_t)(hh0 + 2) * 256 + no],
                       (_Float16)Wo[(size_t)(hh0 + 3) * 256 + no]};
            *(h4_t*)(lds + (it2 * 2 + pr) * 1024 + no * 4) = wv;
        }
    }
    __syncthreads();

    // proj with swapped operands: D = mfma(wf, af) -> D[row=no][col=q];
    // lane holds 4 consecutive no -> float4 store.
    float* outb = out + (size_t)b * (N_OUT * N_OUT);
    for (int nc = 0; nc < 4; nc++) {
        for (int nt = 0; nt < 4; nt++) {
            int no = nc * 64 + nt * 16 + col16;
            h4_t wf[4];
            for (int hk = 0; hk < 4; hk++)
                wf[hk] = *(const h4_t*)(lds + (hk * 4 + quad) * 1024 + no * 4);
            f4_t bb = *(const f4_t*)(bo + nc * 64 + nt * 16 + quad * 4);
            for (int qt = 0; qt < 2; qt++) {
                f4_t a = {};
                for (int hk = 0; hk < 4; hk++)
                    a = __builtin_amdgcn_mfma_f32_16x16x16f16(wf[hk], af[qt][hk], a, 0, 0, 0);
                int q = qbase + qt * 16 + col16;
                int nob = nc * 64 + nt * 16 + quad * 4;
                f4_t v;
                for (int r = 0; r < 4; r++) {
                    float t = a[r] + bb[r];
                    v[r] = (t > 0.f) ? -t : 0.f;
                }
                *(f4_t*)(outb + (size_t)q * N_OUT + nob) = v;
            }
        }
    }
}

// ---------------------------------------------------------------------------
extern "C" void kernel_launch(void* const* d_in, const int* in_sizes, int n_in,
                              void* d_out, int out_size, void* d_ws, size_t ws_size,
                              hipStream_t stream) {
    const float* x = (const float*)d_in[0];
    const float* gamma = (const float*)d_in[1];
    const float* beta = (const float*)d_in[2];
    const float* Wq = (const float*)d_in[3];
    const float* bq = (const float*)d_in[4];
    const float* Wk = (const float*)d_in[5];
    const float* bk = (const float*)d_in[6];
    const float* Wv = (const float*)d_in[7];
    const float* bv = (const float*)d_in[8];
    const float* Wo = (const float*)d_in[9];
    const float* bo = (const float*)d_in[10];
    float* out = (float*)d_out;

    _Float16* h16 = (_Float16*)d_ws;                         // 1 MB
    _Float16* wt16 = h16 + (size_t)B_SZ * N_IN;              // 48 MB
    _Float16* qkv16 = wt16 + (size_t)3 * QKN * N_IN;         // 96 MB

    k_ln<<<dim3(B_SZ / 4), 256, 0, stream>>>(x, gamma, beta, h16);
    k_wt<<<dim3(QKN / 64, N_IN / 64, 3), 256, 0, stream>>>(Wq, Wk, Wv, wt16);
    k_qkv<<<dim3(QKN / 128, B_SZ / 256, 3), 512, 0, stream>>>(h16, wt16, bq, bk, bv, qkv16);
    k_attn<<<dim3(B_SZ), 512, 0, stream>>>(qkv16, Wo, bo, out);
}